// Round 5
// baseline (12.384 us; speedup 1.0000x reference)
//
#include <hip/hip_runtime.h>
#include <math.h>

constexpr int B_ = 4, L_ = 2048, K_ = 64, T_ = 1000;
constexpr int CHUNKS = 32;                 // waves per (b,x0) combo
constexpr int CHUNK_LEN = L_ / CHUNKS;     // 64 positions per wave (1 scan iter)
#define EPSF 1e-6f

__device__ __forceinline__ float wave_sum64(float v) {
#pragma unroll
    for (int o = 32; o; o >>= 1) v += __shfl_xor(v, o, 64);
    return v;
}

// Softmax prob u[lane] of the mixed marginal logits, entirely in probability
// space (see R4 derivation):
//   p_net  = softmax(raw)
//   p_ctrl = (1-tn)*(onehot+EPS) + tn/K
//   u      = ((1-cr)*p_net + cr*p_ctrl) / ((1-cr) + cr*sumc)
// with the reference's w<1e-6 / w>1-1e-6 boundary cases handled explicitly.
__device__ __forceinline__ float get_u(int lane, float we,
                                       const float* __restrict__ W_t,
                                       int tt, int x0) {
    float raw = we + W_t[tt * K_ + lane];   // |raw| <= ~10, exp safe in fp32
    float e = __expf(raw);
    float pnet = e / wave_sum64(e);

    float tn = (float)tt / (float)T_;
    float cr = 2.0f * tn - 1.0f;
    cr *= cr;

    const float onehot = (lane == x0) ? 1.0f + EPSF : EPSF;

    float pctrl, sumc;
    if (tn < 1e-6f) {
        pctrl = onehot;
        sumc = 1.0f + 64.0f * EPSF;
    } else if (tn > 1.0f - 1e-6f) {
        pctrl = 1.0f / (float)K_;
        sumc = 1.0f;
    } else {
        pctrl = (1.0f - tn) * onehot + tn * (1.0f / (float)K_);
        sumc = 1.0f + (1.0f - tn) * 64.0f * EPSF;
    }

    if (cr < 1e-6f) return pnet;
    if (cr > 1.0f - 1e-6f) return pctrl / sumc;
    float pu = (1.0f - cr) * pnet + cr * pctrl;
    float st = (1.0f - cr) + cr * sumc;
    return pu / st;
}

// 4 waves per 256-thread block; each wave owns one (b, x0, chunk): computes
// the (t[b], x0) coupling tables in registers, then ballot-scans its 64
// positions of x_0[b,:] and writes output rows for the matches (each position
// matches exactly one x0 -> exact single coverage).
__global__ __launch_bounds__(256) void fldd_one(
        const float* __restrict__ W_emb,
        const float* __restrict__ W_t,
        const int* __restrict__ x_0,
        const int* __restrict__ x_t,
        const int* __restrict__ t,
        float* __restrict__ out) {
    const int tid = threadIdx.x;
    const int lane = tid & 63;
    const int w = blockIdx.x * 4 + (tid >> 6);   // wave id in [0, 8192)
    const int c = w >> 5;                        // combo id in [0, 256)
    const int chunk = w & (CHUNKS - 1);
    const int b = c >> 6;
    const int x0 = c & 63;

    // Prefetch scan inputs; latency hides under the combo chain.
    const int base = b * L_ + chunk * CHUNK_LEN;
    const int x0v = x_0[base + lane];
    const int xtv = x_t[base + lane];
    const int tb = t[b];

    const float we = W_emb[x0 * K_ + lane];
    const float u_t = get_u(lane, we, W_t, tb, x0);
    const float u_s = get_u(lane, we, W_t, tb - 1, x0);

    const float diff = fmaxf(u_s - u_t, 0.0f);
    const float D = wave_sum64(diff);
    const float mst = diff / (D + EPSF);
    const float S = D / (D + EPSF);                       // sum_k m_st
    const float a  = fminf(u_s, u_t) / (u_t + EPSF);      // prob_stay(j = lane)
    const float pm = fmaxf(u_t - u_s, 0.0f) / (u_t + EPSF); // prob_move(j)
    const float rd = 1.0f / (a + pm * S + EPSF);          // 1/denom(j)

    unsigned long long mask = __ballot(x0v == x0);
    while (mask) {
        const int j = (int)__builtin_ctzll(mask);
        mask &= mask - 1;
        const int pp = base + j;
        const int xt  = __shfl(xtv, j, 64);
        const float aj  = __shfl(a,  xt, 64);
        const float pmj = __shfl(pm, xt, 64);
        const float rdj = __shfl(rd, xt, 64);
        const float q = ((lane == xt) ? aj : 0.0f) + pmj * mst;
        out[pp * K_ + lane] = __logf(fmaf(q, rdj, EPSF));
    }
}

extern "C" void kernel_launch(void* const* d_in, const int* in_sizes, int n_in,
                              void* d_out, int out_size, void* d_ws, size_t ws_size,
                              hipStream_t stream) {
    const float* W_emb = (const float*)d_in[0];
    const float* W_t   = (const float*)d_in[1];
    const int*   x_0   = (const int*)d_in[2];
    const int*   x_t   = (const int*)d_in[3];
    const int*   t     = (const int*)d_in[4];
    float* out = (float*)d_out;

    const int waves = B_ * K_ * CHUNKS;     // 8192 waves
    fldd_one<<<waves / 4, 256, 0, stream>>>(W_emb, W_t, x_0, x_t, t, out);
}

// Round 6
// 9.724 us; speedup vs baseline: 1.2736x; 1.2736x over previous
//
#include <hip/hip_runtime.h>
#include <math.h>

constexpr int B_ = 4, L_ = 2048, K_ = 64, T_ = 1000;
constexpr int CHUNKS = 16;                 // blocks per (b,x0) combo
constexpr int CHUNK_LEN = L_ / CHUNKS;     // 128 positions per block (2 iters of 64)
#define EPSF 1e-6f

__device__ __forceinline__ float wave_sum64(float v) {
#pragma unroll
    for (int o = 32; o; o >>= 1) v += __shfl_xor(v, o, 64);
    return v;
}

// Softmax prob u[lane] of the mixed marginal logits, entirely in probability
// space (R4 derivation):
//   p_net  = softmax(raw)
//   p_ctrl = (1-tn)*(onehot+EPS) + tn/K
//   u      = ((1-cr)*p_net + cr*p_ctrl) / ((1-cr) + cr*sumc)
// with the reference's w<1e-6 / w>1-1e-6 boundary cases handled explicitly.
__device__ __forceinline__ float get_u(int lane, float we,
                                       const float* __restrict__ W_t,
                                       int tt, int x0) {
    float raw = we + W_t[tt * K_ + lane];   // |raw| <= ~10, exp safe in fp32
    float e = __expf(raw);
    float pnet = e / wave_sum64(e);

    float tn = (float)tt / (float)T_;
    float cr = 2.0f * tn - 1.0f;
    cr *= cr;

    const float onehot = (lane == x0) ? 1.0f + EPSF : EPSF;

    float pctrl, sumc;
    if (tn < 1e-6f) {
        pctrl = onehot;
        sumc = 1.0f + 64.0f * EPSF;
    } else if (tn > 1.0f - 1e-6f) {
        pctrl = 1.0f / (float)K_;
        sumc = 1.0f;
    } else {
        pctrl = (1.0f - tn) * onehot + tn * (1.0f / (float)K_);
        sumc = 1.0f + (1.0f - tn) * 64.0f * EPSF;
    }

    if (cr < 1e-6f) return pnet;
    if (cr > 1.0f - 1e-6f) return pctrl / sumc;
    float pu = (1.0f - cr) * pnet + cr * pctrl;
    float st = (1.0f - cr) + cr * sumc;
    return pu / st;
}

// One wave per (b, x0, chunk). Wave computes the coupling tables for its
// (t[b], x0) combo in registers, then ballot-scans its chunk of x_0[b,:] and
// writes output rows for matching positions (each position matches exactly
// one x0 -> exact single coverage).
__global__ __launch_bounds__(64) void fldd_one(
        const float* __restrict__ W_emb,
        const float* __restrict__ W_t,
        const int* __restrict__ x_0,
        const int* __restrict__ x_t,
        const int* __restrict__ t,
        float* __restrict__ out) {
    const int lane = threadIdx.x;
    const int blk = blockIdx.x;
    const int c = blk >> 4;                 // combo id in [0, 256)
    const int chunk = blk & (CHUNKS - 1);
    const int b = c >> 6;
    const int x0 = c & 63;

    // Prefetch scan inputs so their latency hides under the combo chain.
    const int base = b * L_ + chunk * CHUNK_LEN;
    const int x0v0 = x_0[base + lane];
    const int xtv0 = x_t[base + lane];
    const int x0v1 = x_0[base + 64 + lane];
    const int xtv1 = x_t[base + 64 + lane];
    const int tb = t[b];

    const float we = W_emb[x0 * K_ + lane];
    const float u_t = get_u(lane, we, W_t, tb, x0);
    const float u_s = get_u(lane, we, W_t, tb - 1, x0);

    const float diff = fmaxf(u_s - u_t, 0.0f);
    const float D = wave_sum64(diff);
    const float mst = diff / (D + EPSF);
    const float S = D / (D + EPSF);                       // sum_k m_st
    const float a  = fminf(u_s, u_t) / (u_t + EPSF);      // prob_stay(j = lane)
    const float pm = fmaxf(u_t - u_s, 0.0f) / (u_t + EPSF); // prob_move(j)
    const float rd = 1.0f / (a + pm * S + EPSF);          // 1/denom(j)

#pragma unroll
    for (int it = 0; it < 2; ++it) {
        const int x0v = it ? x0v1 : x0v0;
        const int xtv = it ? xtv1 : xtv0;
        unsigned long long mask = __ballot(x0v == x0);
        while (mask) {
            const int j = (int)__builtin_ctzll(mask);
            mask &= mask - 1;
            const int pp = base + it * 64 + j;
            const int xt  = __shfl(xtv, j, 64);
            const float aj  = __shfl(a,  xt, 64);
            const float pmj = __shfl(pm, xt, 64);
            const float rdj = __shfl(rd, xt, 64);
            const float q = ((lane == xt) ? aj : 0.0f) + pmj * mst;
            out[pp * K_ + lane] = __logf(fmaf(q, rdj, EPSF));
        }
    }
}

extern "C" void kernel_launch(void* const* d_in, const int* in_sizes, int n_in,
                              void* d_out, int out_size, void* d_ws, size_t ws_size,
                              hipStream_t stream) {
    const float* W_emb = (const float*)d_in[0];
    const float* W_t   = (const float*)d_in[1];
    const int*   x_0   = (const int*)d_in[2];
    const int*   x_t   = (const int*)d_in[3];
    const int*   t     = (const int*)d_in[4];
    float* out = (float*)d_out;

    const int blocks = B_ * K_ * CHUNKS;    // 4096 blocks, 1 wave each
    fldd_one<<<blocks, 64, 0, stream>>>(W_emb, W_t, x_0, x_t, t, out);
}

// Round 7
// 9.609 us; speedup vs baseline: 1.2887x; 1.0119x over previous
//
#include <hip/hip_runtime.h>
#include <math.h>

constexpr int B_ = 4, L_ = 2048, K_ = 64, T_ = 1000;
constexpr int CHUNKS = 16;                 // scan-chunks per (b,x0) combo
constexpr int CHUNK_LEN = L_ / CHUNKS;     // 128 positions per scan-wave
#define EPSF 1e-6f

__device__ __forceinline__ float wave_sum64(float v) {
#pragma unroll
    for (int o = 32; o; o >>= 1) v += __shfl_xor(v, o, 64);
    return v;
}

// Softmax prob u[lane] of the mixed marginal logits, entirely in probability
// space (R4 derivation); reference's w<1e-6 / w>1-1e-6 boundaries explicit.
__device__ __forceinline__ float get_u(int lane, float we,
                                       const float* __restrict__ W_t,
                                       int tt, int x0) {
    float raw = we + W_t[tt * K_ + lane];   // |raw| <= ~10, exp safe in fp32
    float e = __expf(raw);
    float pnet = e / wave_sum64(e);

    float tn = (float)tt / (float)T_;
    float cr = 2.0f * tn - 1.0f;
    cr *= cr;

    const float onehot = (lane == x0) ? 1.0f + EPSF : EPSF;

    float pctrl, sumc;
    if (tn < 1e-6f) {
        pctrl = onehot;
        sumc = 1.0f + 64.0f * EPSF;
    } else if (tn > 1.0f - 1e-6f) {
        pctrl = 1.0f / (float)K_;
        sumc = 1.0f;
    } else {
        pctrl = (1.0f - tn) * onehot + tn * (1.0f / (float)K_);
        sumc = 1.0f + (1.0f - tn) * 64.0f * EPSF;
    }

    if (cr < 1e-6f) return pnet;
    if (cr > 1.0f - 1e-6f) return pctrl / sumc;
    float pu = (1.0f - cr) * pnet + cr * pctrl;
    float st = (1.0f - cr) + cr * sumc;
    return pu / st;
}

// 1024 blocks x 256 threads. Each block owns one (combo, chunk-group):
// wave 0 computes the (t[b], x0) coupling tables ONCE, shares them via LDS;
// all 4 waves then ballot-scan their own 128-position chunk of x_0[b,:] and
// write output rows for matches (each position matches exactly one x0).
__global__ __launch_bounds__(256) void fldd_one(
        const float* __restrict__ W_emb,
        const float* __restrict__ W_t,
        const int* __restrict__ x_0,
        const int* __restrict__ x_t,
        const int* __restrict__ t,
        float* __restrict__ out) {
    const int tid = threadIdx.x;
    const int lane = tid & 63;
    const int wv = tid >> 6;                // wave in block, 0..3
    const int blk = blockIdx.x;
    const int c = blk >> 2;                 // combo id in [0, 256)
    const int cg = blk & 3;                 // chunk-group
    const int chunk = cg * 4 + wv;          // this wave's chunk, 0..15
    const int b = c >> 6;
    const int x0 = c & 63;

    __shared__ float s_mst[64], s_a[64], s_pm[64], s_rd[64];

    // Every wave prefetches its scan inputs before the barrier.
    const int base = b * L_ + chunk * CHUNK_LEN;
    const int x0v0 = x_0[base + lane];
    const int xtv0 = x_t[base + lane];
    const int x0v1 = x_0[base + 64 + lane];
    const int xtv1 = x_t[base + 64 + lane];

    if (wv == 0) {
        const int tb = t[b];
        const float we = W_emb[x0 * K_ + lane];
        const float u_t = get_u(lane, we, W_t, tb, x0);
        const float u_s = get_u(lane, we, W_t, tb - 1, x0);

        const float diff = fmaxf(u_s - u_t, 0.0f);
        const float D = wave_sum64(diff);
        const float S = D / (D + EPSF);                      // sum_k m_st
        const float a  = fminf(u_s, u_t) / (u_t + EPSF);     // prob_stay(j=lane)
        const float pm = fmaxf(u_t - u_s, 0.0f) / (u_t + EPSF);
        s_mst[lane] = diff / (D + EPSF);
        s_a[lane] = a;
        s_pm[lane] = pm;
        s_rd[lane] = 1.0f / (a + pm * S + EPSF);             // 1/denom(j)
    }
    __syncthreads();

    const float mst = s_mst[lane];
    const float a   = s_a[lane];
    const float pm  = s_pm[lane];
    const float rd  = s_rd[lane];

#pragma unroll
    for (int it = 0; it < 2; ++it) {
        const int x0v = it ? x0v1 : x0v0;
        const int xtv = it ? xtv1 : xtv0;
        unsigned long long mask = __ballot(x0v == x0);
        while (mask) {
            const int j = (int)__builtin_ctzll(mask);
            mask &= mask - 1;
            const int pp = base + it * 64 + j;
            const int xt  = __shfl(xtv, j, 64);
            const float aj  = __shfl(a,  xt, 64);
            const float pmj = __shfl(pm, xt, 64);
            const float rdj = __shfl(rd, xt, 64);
            const float q = ((lane == xt) ? aj : 0.0f) + pmj * mst;
            out[pp * K_ + lane] = __logf(fmaf(q, rdj, EPSF));
        }
    }
}

extern "C" void kernel_launch(void* const* d_in, const int* in_sizes, int n_in,
                              void* d_out, int out_size, void* d_ws, size_t ws_size,
                              hipStream_t stream) {
    const float* W_emb = (const float*)d_in[0];
    const float* W_t   = (const float*)d_in[1];
    const int*   x_0   = (const int*)d_in[2];
    const int*   x_t   = (const int*)d_in[3];
    const int*   t     = (const int*)d_in[4];
    float* out = (float*)d_out;

    const int blocks = B_ * K_ * 4;         // 1024 blocks, 4 waves each
    fldd_one<<<blocks, 256, 0, stream>>>(W_emb, W_t, x_0, x_t, t, out);
}